// Round 1
// baseline (360.813 us; speedup 1.0000x reference)
//
#include <hip/hip_runtime.h>

#define NPTS 65552          // 16 * (64*64 + 1)
#define MPAD 65664          // 513 * 128
#define NVOX 274625         // 65^3

typedef unsigned short u16;
typedef __attribute__((ext_vector_type(8))) short bf16x8;
typedef __attribute__((ext_vector_type(4))) float f32x4;
typedef __attribute__((ext_vector_type(4))) unsigned short us4;

__device__ __forceinline__ u16 f2bf(float f) {
  unsigned int u = __float_as_uint(f);
  return (u16)((u + 0x7FFFu + ((u >> 16) & 1u)) >> 16);
}

// ---------------- coords from depth ----------------
__global__ void coords_kernel(const float* __restrict__ depth, int* __restrict__ pcoord) {
  int b = blockIdx.x, tid = threadIdx.x;
  const float* d = depth + b * 4096;
  float mn = 1e30f, mx = -1e30f;
  for (int p = tid; p < 4096; p += 256) {
    float v = d[p];
    mn = fminf(mn, v);
    mx = fmaxf(mx, v);
  }
  __shared__ float smn[256], smx[256];
  smn[tid] = mn; smx[tid] = mx;
  __syncthreads();
  for (int s = 128; s > 0; s >>= 1) {
    if (tid < s) {
      smn[tid] = fminf(smn[tid], smn[tid + s]);
      smx[tid] = fmaxf(smx[tid], smx[tid + s]);
    }
    __syncthreads();
  }
  mn = smn[0]; mx = smx[0];
  float den = mx - mn + 1e-8f;
  for (int p = tid; p < 4096; p += 256) {
    int i = p >> 6, j = p & 63;
    float x = (float)j / 63.0f;       // matches jnp arange/63 (IEEE div)
    float y = (float)i / 63.0f;
    float z = (d[p] - mn) / den;
    int cx = (int)rintf(x * 64.0f);   // *64 exact, rintf = round-half-even
    int cy = (int)rintf(y * 64.0f);
    int cz = (int)rintf(z * 64.0f);
    cx = min(max(cx, 0), 64); cy = min(max(cy, 0), 64); cz = min(max(cz, 0), 64);
    pcoord[b * 4097 + 1 + p] = cx | (cy << 8) | (cz << 16);
  }
  if (tid == 0) pcoord[b * 4097] = 0;   // cls token coord (0,0,0)
}

// ---------------- voxel map ----------------
__global__ void init_idx(int* __restrict__ m) {
  int i = blockIdx.x * 256 + threadIdx.x;
  if (i < NVOX) m[i] = -1;
}

__global__ void scatter_idx(const int* __restrict__ pcoord, int* __restrict__ m) {
  int n = blockIdx.x * 256 + threadIdx.x;
  if (n >= NPTS) return;
  int c = pcoord[n];
  int lin = ((c & 255) * 65 + ((c >> 8) & 255)) * 65 + ((c >> 16) & 255);
  atomicMax(&m[lin], n);
}

// ---------------- neighbor ids: nid[k][n], invalid -> NPTS (zero row) ----------------
__global__ void nbr_kernel(const int* __restrict__ pcoord, const int* __restrict__ m,
                           int* __restrict__ nid) {
  int n = blockIdx.x * 256 + threadIdx.x;
  if (n >= MPAD) return;
  if (n >= NPTS) {
    for (int k = 0; k < 27; ++k) nid[k * MPAD + n] = NPTS;
    return;
  }
  int c = pcoord[n];
  int cx = c & 255, cy = (c >> 8) & 255, cz = (c >> 16) & 255;
#pragma unroll
  for (int k = 0; k < 27; ++k) {
    int nx = cx + k / 9 - 1;
    int ny = cy + (k / 3) % 3 - 1;
    int nz = cz + k % 3 - 1;
    int id = NPTS;
    if (((unsigned)nx <= 64u) && ((unsigned)ny <= 64u) && ((unsigned)nz <= 64u)) {
      int v = m[(nx * 65 + ny) * 65 + nz];
      if (v >= 0) id = v;
    }
    nid[k * MPAD + n] = id;
  }
}

// ---------------- features fp32 -> bf16 (+ zero row at NPTS) ----------------
__global__ void conv_feat(const float* __restrict__ f, u16* __restrict__ o) {
  int q = blockIdx.x * 256 + threadIdx.x;       // quad index
  if (q >= (NPTS + 1) * 64) return;
  us4 r;
  if (q < NPTS * 64) {
    float4 v = ((const float4*)f)[q];
    r.x = f2bf(v.x); r.y = f2bf(v.y); r.z = f2bf(v.z); r.w = f2bf(v.w);
  } else {
    r.x = 0; r.y = 0; r.z = 0; r.w = 0;
  }
  ((us4*)o)[q] = r;
}

// ---------------- weight fp32 [27][ci][co] -> bf16 transposed [27][co][ci] ----------------
__global__ void conv_wt(const float* __restrict__ w, u16* __restrict__ wt) {
  __shared__ float t[32][33];
  int k = blockIdx.x, cib = blockIdx.y * 32, cob = blockIdx.z * 32;
  int tx = threadIdx.x, ty = threadIdx.y;       // 32 x 8
  const float* Wk = w + k * 65536;
#pragma unroll
  for (int r = 0; r < 4; ++r)
    t[ty + r * 8][tx] = Wk[(cib + ty + r * 8) * 256 + cob + tx];
  __syncthreads();
  u16* Wt = wt + k * 65536;
#pragma unroll
  for (int r = 0; r < 4; ++r)
    Wt[(cob + ty + r * 8) * 256 + cib + tx] = f2bf(t[tx][ty + r * 8]);
}

// ---------------- gather-GEMM: out[N,256] = sum_k gather(feat, nid_k) @ W_k ----------------
__device__ __forceinline__ void gload16(const void* g, unsigned int lds_off) {
  __builtin_amdgcn_global_load_lds(
      (__attribute__((address_space(1))) void*)(size_t)g,
      (__attribute__((address_space(3))) void*)(unsigned int)lds_off,
      16, 0, 0);
}

__global__ __launch_bounds__(512) void gemm_kernel(const u16* __restrict__ feat,
                                                   const u16* __restrict__ wt,
                                                   const int* __restrict__ nid,
                                                   float* __restrict__ out) {
  __shared__ u16 As[128 * 32];     // [row 128][k 32]
  __shared__ u16 Bs[256 * 32];     // [co 256][k 32]
  int bm = blockIdx.x;
  int tid = threadIdx.x;
  int w = tid >> 6, l = tid & 63;
  int wr = w >> 2, wc = w & 3;     // wave tile (wr*64, wc*64)
  int lm = l & 15, lk = l >> 4;

  // staging lane mapping
  int rA = (w << 4) + (l >> 2);    // A row this lane stages (1 chunk/wave)
  int rB = (w << 5) + (l >> 2);    // B first-chunk row (2 chunks/wave)
  int cb = (l & 3) << 4;           // byte offset within 64B row
  int gmA = bm * 128 + rA;

  unsigned int asBase = (unsigned int)(size_t)(&As[0]) + (unsigned int)(w * 1024);
  unsigned int bsBase = (unsigned int)(size_t)(&Bs[0]) + (unsigned int)(w * 2048);

  const char* featc = (const char*)feat;
  const char* wtc = (const char*)wt;

  f32x4 acc[4][4];
#pragma unroll
  for (int m = 0; m < 4; ++m)
#pragma unroll
    for (int n = 0; n < 4; ++n) acc[m][n] = (f32x4){0.f, 0.f, 0.f, 0.f};

  const bf16x8* Av = (const bf16x8*)As;
  const bf16x8* Bv = (const bf16x8*)Bs;

  int nv_next = nid[gmA];          // prefetch ko=0
  for (int ko = 0; ko < 27; ++ko) {
    int nv = nv_next;
    if (ko < 26) nv_next = nid[(ko + 1) * MPAD + gmA];   // hide latency under 8 K-steps
    size_t aoff = (size_t)nv << 9;                       // *512 bytes/row
    int boff = ko * 131072 + (rB << 9);
#pragma unroll
    for (int ks = 0; ks < 8; ++ks) {
      int kb = ks << 6;
      gload16(featc + aoff + kb + cb, asBase);               // A gather chunk
      gload16(wtc + boff + kb + cb, bsBase);                 // B chunk 0
      gload16(wtc + boff + 8192 + kb + cb, bsBase + 1024);   // B chunk 1
      __syncthreads();   // vmcnt(0) drain -> tiles valid
      bf16x8 a[4], b[4];
#pragma unroll
      for (int m = 0; m < 4; ++m) a[m] = Av[((wr << 6) + (m << 4) + lm) * 4 + lk];
#pragma unroll
      for (int n = 0; n < 4; ++n) b[n] = Bv[((wc << 6) + (n << 4) + lm) * 4 + lk];
#pragma unroll
      for (int m = 0; m < 4; ++m)
#pragma unroll
        for (int n = 0; n < 4; ++n)
          acc[m][n] = __builtin_amdgcn_mfma_f32_16x16x32_bf16(a[m], b[n], acc[m][n], 0, 0, 0);
      __syncthreads();   // reads done before next stage overwrites
    }
  }

  // epilogue: D row = (lk*4+i), col = lm within each 16x16 frag
#pragma unroll
  for (int m = 0; m < 4; ++m) {
#pragma unroll
    for (int i = 0; i < 4; ++i) {
      int gr = bm * 128 + (wr << 6) + (m << 4) + (lk << 2) + i;
      if (gr < NPTS) {
        float* po = out + (size_t)gr * 256 + (wc << 6) + lm;
#pragma unroll
        for (int n = 0; n < 4; ++n) po[n << 4] = acc[m][n][i];
      }
    }
  }
}

extern "C" void kernel_launch(void* const* d_in, const int* in_sizes, int n_in,
                              void* d_out, int out_size, void* d_ws, size_t ws_size,
                              hipStream_t stream) {
  const float* features = (const float*)d_in[0];
  const float* depth = (const float*)d_in[1];
  const float* weight = (const float*)d_in[2];
  float* out = (float*)d_out;
  char* ws = (char*)d_ws;

  // ws layout (256B aligned)
  int* idx_map = (int*)(ws + 0);              // 274625 ints
  int* pcoord  = (int*)(ws + 1098752);        // 65552 ints
  int* nid     = (int*)(ws + 1361152);        // 27*65664 ints
  u16* feat_bf = (u16*)(ws + 8452864);        // (65552+1)*256 bf16
  u16* wt_bf   = (u16*)(ws + 42016256);       // 27*256*256 bf16
  // total ~45.6 MB

  coords_kernel<<<16, 256, 0, stream>>>(depth, pcoord);
  init_idx<<<(NVOX + 255) / 256, 256, 0, stream>>>(idx_map);
  scatter_idx<<<(NPTS + 255) / 256, 256, 0, stream>>>(pcoord, idx_map);
  nbr_kernel<<<(MPAD + 255) / 256, 256, 0, stream>>>(pcoord, idx_map, nid);
  conv_feat<<<((NPTS + 1) * 64 + 255) / 256, 256, 0, stream>>>(features, feat_bf);
  conv_wt<<<dim3(27, 8, 8), dim3(32, 8), 0, stream>>>(weight, wt_bf);
  gemm_kernel<<<513, 512, 0, stream>>>(feat_bf, wt_bf, nid, out);
}